// Round 1
// baseline (2021.221 us; speedup 1.0000x reference)
//
#include <hip/hip_runtime.h>
#include <math.h>

#define TPB 256
#define CAND_CAP 262144u

__device__ __forceinline__ float lrelu(float v){ return v >= 0.0f ? v : 0.01f*v; }
__device__ __forceinline__ unsigned fkey(float f){
  unsigned b = __float_as_uint(f);
  return (b & 0x80000000u) ? ~b : (b | 0x80000000u);
}

// ---------------- gemm1: h1 = x @ W1 (128->16), fused dst-degree histogram ----------------
__global__ __launch_bounds__(TPB) void k_gemm1_hist(
    const float* __restrict__ x, const float* __restrict__ W1,
    float* __restrict__ h1, int N,
    const int* __restrict__ dst, int E, int* __restrict__ cnt)
{
  __shared__ float Ws[2048]; // transposed: Ws[c*128+k]
  for (int idx = threadIdx.x; idx < 2048; idx += TPB){
    int k = idx >> 4, c = idx & 15;
    Ws[c*128 + k] = W1[idx];
  }
  __syncthreads();
  int base = blockIdx.x*1024 + threadIdx.x;
  int nn[4]; bool val[4];
  #pragma unroll
  for (int j=0;j<4;++j){ nn[j] = base + j*TPB; val[j] = nn[j] < N; }
  float acc[4][16];
  #pragma unroll
  for (int j=0;j<4;++j)
    #pragma unroll
    for (int c=0;c<16;++c) acc[j][c]=0.f;
  for (int k4=0;k4<32;++k4){
    float4 xv[4];
    #pragma unroll
    for (int j=0;j<4;++j)
      xv[j] = val[j] ? ((const float4*)(x + (size_t)nn[j]*128))[k4] : make_float4(0.f,0.f,0.f,0.f);
    #pragma unroll
    for (int c=0;c<16;++c){
      float4 wv = *(const float4*)&Ws[c*128 + k4*4];
      #pragma unroll
      for (int j=0;j<4;++j)
        acc[j][c] += xv[j].x*wv.x + xv[j].y*wv.y + xv[j].z*wv.z + xv[j].w*wv.w;
    }
  }
  #pragma unroll
  for (int j=0;j<4;++j) if (val[j]){
    float4* op = (float4*)(h1 + (size_t)nn[j]*16);
    #pragma unroll
    for (int q=0;q<4;++q)
      op[q] = make_float4(acc[j][q*4+0],acc[j][q*4+1],acc[j][q*4+2],acc[j][q*4+3]);
  }
  // histogram of dst (for CSR build)
  int stride = gridDim.x*TPB;
  for (int e = blockIdx.x*TPB + threadIdx.x; e < E; e += stride)
    atomicAdd(&cnt[dst[e]], 1);
}

// ---------------- CSR row allocation: block scan + one global atomic per block ----------------
__global__ __launch_bounds__(TPB) void k_alloc(
    const int* __restrict__ cnt, int* __restrict__ row_start,
    int* __restrict__ cursor, int N, unsigned* __restrict__ ctrl)
{
  __shared__ int sc[TPB];
  __shared__ int sbase;
  int i = blockIdx.x*TPB + threadIdx.x;
  int c = (i < N) ? cnt[i] : 0;
  int v = c;
  sc[threadIdx.x] = v;
  __syncthreads();
  for (int off=1; off<TPB; off<<=1){
    int add = (threadIdx.x >= off) ? sc[threadIdx.x-off] : 0;
    __syncthreads();
    v += add;
    sc[threadIdx.x] = v;
    __syncthreads();
  }
  if (threadIdx.x == TPB-1) sbase = (int)atomicAdd(&ctrl[0], (unsigned)v);
  __syncthreads();
  if (i < N){
    int start = sbase + (v - c); // exclusive prefix
    row_start[i] = start;
    cursor[i] = start;
  }
}

// ---------------- counting-sort scatter: col[] = src sorted by dst ----------------
__global__ __launch_bounds__(TPB) void k_scatter(
    const int* __restrict__ src, const int* __restrict__ dst, int E,
    int* __restrict__ cursor, int* __restrict__ col)
{
  int e = blockIdx.x*TPB + threadIdx.x;
  if (e >= E) return;
  int d = dst[e];
  int slot = atomicAdd(&cursor[d], 1);
  col[slot] = src[e];
}

// ---------------- conv1 aggregation (gather, no atomics) + BN stats ----------------
__global__ __launch_bounds__(TPB) void k_conv1agg(
    const float* __restrict__ h1, const int* __restrict__ rs,
    const int* __restrict__ re, const int* __restrict__ col,
    float* __restrict__ agg, int N, float* __restrict__ stats)
{
  __shared__ float red[TPB][17];
  int i = blockIdx.x*TPB + threadIdx.x;
  float a[16];
  #pragma unroll
  for (int c=0;c<16;++c) a[c]=0.f;
  if (i < N){
    int b = rs[i], e = re[i];
    for (int t=b;t<e;++t){
      const float4* hp = (const float4*)(h1 + (size_t)col[t]*16);
      float4 v0=hp[0], v1=hp[1], v2=hp[2], v3=hp[3];
      a[0]+=v0.x; a[1]+=v0.y; a[2]+=v0.z; a[3]+=v0.w;
      a[4]+=v1.x; a[5]+=v1.y; a[6]+=v1.z; a[7]+=v1.w;
      a[8]+=v2.x; a[9]+=v2.y; a[10]+=v2.z; a[11]+=v2.w;
      a[12]+=v3.x; a[13]+=v3.y; a[14]+=v3.z; a[15]+=v3.w;
    }
    float4* op = (float4*)(agg + (size_t)i*16);
    op[0]=make_float4(a[0],a[1],a[2],a[3]);
    op[1]=make_float4(a[4],a[5],a[6],a[7]);
    op[2]=make_float4(a[8],a[9],a[10],a[11]);
    op[3]=make_float4(a[12],a[13],a[14],a[15]);
  }
  #pragma unroll
  for (int c=0;c<16;++c) red[threadIdx.x][c]=a[c];
  __syncthreads();
  if (threadIdx.x < 32){
    int c = threadIdx.x & 15, r0 = (threadIdx.x>>4)*128;
    float sm=0.f, q=0.f;
    for (int r=0;r<128;++r){ float v = red[r0+r][c]; sm+=v; q+=v*v; }
    atomicAdd(&stats[c], sm);
    atomicAdd(&stats[16+c], q);
  }
}

// ---------------- BN1 + lrelu (in place) + p1 = h.Wrel, s1 = h.Wroot + br ----------------
__global__ __launch_bounds__(TPB) void k_bn1(
    float* __restrict__ h, const float* __restrict__ stats,
    const float* __restrict__ g, const float* __restrict__ be,
    const float* __restrict__ Wr, const float* __restrict__ br,
    const float* __restrict__ Wroot,
    float* __restrict__ p, float* __restrict__ s, int N, float invn)
{
  int i = blockIdx.x*TPB + threadIdx.x;
  if (i >= N) return;
  float* hp = h + (size_t)i*16;
  float pv=0.f, rv=0.f;
  #pragma unroll
  for (int c=0;c<16;++c){
    float mu = stats[c]*invn;
    float var = stats[16+c]*invn - mu*mu;
    float rsd = 1.0f / sqrtf(var + 1e-5f);
    float v = (hp[c]-mu)*rsd*g[c] + be[c];
    v = lrelu(v);
    hp[c] = v;
    pv += v*Wr[c];
    rv += v*Wroot[c];
  }
  p[i] = pv;
  s[i] = rv + br[0];
}

// ---------------- scalar score aggregation: s[i] += sum p[col[e]] (optionally masked) --------
__global__ __launch_bounds__(TPB) void k_scoreagg(
    const float* __restrict__ p, const int* __restrict__ rs,
    const int* __restrict__ re, const int* __restrict__ col,
    float* __restrict__ s, const unsigned char* __restrict__ keep, int N)
{
  int i = blockIdx.x*TPB + threadIdx.x;
  if (i >= N) return;
  if (keep && !keep[i]) return;
  float sum = s[i];
  int b = rs[i], e = re[i];
  for (int t=b;t<e;++t){
    int sd = col[t];
    if (!keep || keep[sd]) sum += p[sd];
  }
  s[i] = sum;
}

// ---------------- radix-select stage 1: monotonic keys + top-16-bit histogram ----------------
__global__ __launch_bounds__(TPB) void k_keyhist(
    const float* __restrict__ s, const unsigned char* __restrict__ keep,
    unsigned* __restrict__ ukey, unsigned* __restrict__ hist, int N)
{
  int i = blockIdx.x*TPB + threadIdx.x;
  if (i >= N) return;
  unsigned u = 0u;
  if (!keep || keep[i]) u = fkey(s[i]);
  ukey[i] = u;
  if (u) atomicAdd(&hist[u>>16], 1u);
}

// ---------------- find threshold bucket (1 block) ----------------
__global__ __launch_bounds__(TPB) void k_findbucket(
    const unsigned* __restrict__ hist, unsigned k, unsigned* __restrict__ ctrl)
{
  __shared__ unsigned seg[TPB];
  unsigned t = threadIdx.x;
  unsigned ssum = 0;
  for (int b=0;b<256;++b) ssum += hist[t*256 + b];
  seg[t] = ssum;
  __syncthreads();
  if (t == 0){
    unsigned cum = 0; int S = 255;
    for (int s2=255; s2>=0; --s2){
      if (cum + seg[s2] >= k){ S = s2; break; }
      cum += seg[s2];
    }
    unsigned B = 0, need = 0;
    for (int b=255;b>=0;--b){
      unsigned h = hist[S*256 + b];
      if (cum + h >= k){ B = (unsigned)(S*256 + b); need = k - cum; break; }
      cum += h;
    }
    ctrl[1] = B;
    ctrl[2] = need;
  }
}

// ---------------- collect boundary-bucket candidates; also re-zero hist for next use --------
__global__ __launch_bounds__(TPB) void k_collect(
    const unsigned* __restrict__ ukey, unsigned* __restrict__ cand,
    unsigned* __restrict__ ctrl, unsigned* __restrict__ hist, int N)
{
  int i = blockIdx.x*TPB + threadIdx.x;
  if (i < 65536) hist[i] = 0u;
  if (i < N){
    unsigned u = ukey[i];
    if ((u>>16) == ctrl[1]){
      unsigned pos = atomicAdd(&ctrl[6], 1u);
      if (pos < CAND_CAP) cand[pos] = u;
    }
  }
}

// ---------------- refine low 16 bits (1 block) -> T, needT; resets tie & cand counters ------
__global__ __launch_bounds__(TPB) void k_refine(
    const unsigned* __restrict__ cand, unsigned* __restrict__ ctrl)
{
  __shared__ unsigned h8[256];
  __shared__ unsigned sB2, sN2;
  unsigned t = threadIdx.x;
  unsigned L = ctrl[6];
  unsigned need = ctrl[2];
  h8[t] = 0u; __syncthreads();
  for (unsigned i=t; i<L; i+=TPB) atomicAdd(&h8[(cand[i]>>8)&0xFFu], 1u);
  __syncthreads();
  if (t == 0){
    unsigned cum=0, B2=0, n2=need;
    for (int b=255;b>=0;--b){
      unsigned h = h8[b];
      if (cum + h >= need){ B2=(unsigned)b; n2 = need - cum; break; }
      cum += h;
    }
    sB2 = B2; sN2 = n2;
  }
  __syncthreads();
  unsigned B2 = sB2, need2 = sN2;
  h8[t] = 0u; __syncthreads();
  for (unsigned i=t; i<L; i+=TPB){
    unsigned u = cand[i];
    if (((u>>8)&0xFFu) == B2) atomicAdd(&h8[u&0xFFu], 1u);
  }
  __syncthreads();
  if (t == 0){
    unsigned cum=0, B3=0, n3=need2;
    for (int b=255;b>=0;--b){
      unsigned h = h8[b];
      if (cum + h >= need2){ B3=(unsigned)b; n3 = need2 - cum; break; }
      cum += h;
    }
    unsigned B = ctrl[1];
    ctrl[3] = (B<<16) | (B2<<8) | B3; // threshold key T
    ctrl[4] = n3;                    // how many ==T to take
    ctrl[5] = 0u;                    // tie counter
    ctrl[6] = 0u;                    // cand counter (for next selection)
  }
}

// ---------------- mark keep1 + z1 = keep ? h1p * tanh(s1) : 0 ----------------
__global__ __launch_bounds__(TPB) void k_mark1(
    const unsigned* __restrict__ ukey, const float* __restrict__ s1,
    const float* __restrict__ h1p, float* __restrict__ z1,
    unsigned char* __restrict__ keep, unsigned* __restrict__ ctrl, int N)
{
  int i = blockIdx.x*TPB + threadIdx.x;
  if (i >= N) return;
  unsigned u = ukey[i], T = ctrl[3], needT = ctrl[4];
  bool sel = u > T;
  if (!sel && u == T) sel = (atomicAdd(&ctrl[5], 1u) < needT);
  keep[i] = sel ? (unsigned char)1 : (unsigned char)0;
  float tv = sel ? tanhf(s1[i]) : 0.0f;
  const float4* hp = (const float4*)(h1p + (size_t)i*16);
  float4* zp = (float4*)(z1 + (size_t)i*16);
  #pragma unroll
  for (int q=0;q<4;++q){
    float4 v = hp[q];
    zp[q] = make_float4(v.x*tv, v.y*tv, v.z*tv, v.w*tv);
  }
}

// ---------------- conv2: masked 16-dim aggregation + GEMM 16->32 + BN stats, fused ----------
__global__ __launch_bounds__(TPB) void k_conv2(
    const float* __restrict__ z1, const int* __restrict__ rs,
    const int* __restrict__ re, const int* __restrict__ col,
    const unsigned char* __restrict__ keep, const float* __restrict__ W2,
    float* __restrict__ h2, int N, float* __restrict__ stats)
{
  __shared__ float W2s[512];
  __shared__ float red[TPB][33];
  for (int idx=threadIdx.x; idx<512; idx+=TPB) W2s[idx] = W2[idx];
  __syncthreads();
  int i = blockIdx.x*TPB + threadIdx.x;
  float a[16];
  #pragma unroll
  for (int c=0;c<16;++c) a[c]=0.f;
  bool act = (i < N) && keep[i];
  if (act){
    int b = rs[i], e = re[i];
    for (int t=b;t<e;++t){
      int sd = col[t];
      if (keep[sd]){
        const float4* zp = (const float4*)(z1 + (size_t)sd*16);
        float4 v0=zp[0], v1=zp[1], v2=zp[2], v3=zp[3];
        a[0]+=v0.x; a[1]+=v0.y; a[2]+=v0.z; a[3]+=v0.w;
        a[4]+=v1.x; a[5]+=v1.y; a[6]+=v1.z; a[7]+=v1.w;
        a[8]+=v2.x; a[9]+=v2.y; a[10]+=v2.z; a[11]+=v2.w;
        a[12]+=v3.x; a[13]+=v3.y; a[14]+=v3.z; a[15]+=v3.w;
      }
    }
  }
  float h[32];
  #pragma unroll
  for (int c2=0;c2<32;++c2) h[c2]=0.f;
  #pragma unroll
  for (int c=0;c<16;++c){
    float av = a[c];
    const float* wrow = &W2s[c*32];
    #pragma unroll
    for (int c2=0;c2<32;++c2) h[c2] += av*wrow[c2];
  }
  if (act){
    float4* op = (float4*)(h2 + (size_t)i*32);
    #pragma unroll
    for (int q=0;q<8;++q)
      op[q] = make_float4(h[q*4+0],h[q*4+1],h[q*4+2],h[q*4+3]);
  }
  #pragma unroll
  for (int c2=0;c2<32;++c2) red[threadIdx.x][c2]=h[c2];
  __syncthreads();
  if (threadIdx.x < 64){
    int c = threadIdx.x & 31, r0 = (threadIdx.x>>5)*128;
    float sm=0.f, q=0.f;
    for (int r=0;r<128;++r){ float v = red[r0+r][c]; sm+=v; q+=v*v; }
    atomicAdd(&stats[c], sm);
    atomicAdd(&stats[32+c], q);
  }
}

// ---------------- BN2 + lrelu (in place, kept only) + p2, s2 ----------------
__global__ __launch_bounds__(TPB) void k_bn2(
    float* __restrict__ h, const float* __restrict__ stats,
    const float* __restrict__ g, const float* __restrict__ be,
    const float* __restrict__ Wr, const float* __restrict__ br,
    const float* __restrict__ Wroot, const unsigned char* __restrict__ keep,
    float* __restrict__ p, float* __restrict__ s, int N, float invn)
{
  int i = blockIdx.x*TPB + threadIdx.x;
  if (i >= N) return;
  if (!keep[i]) return;
  float* hp = h + (size_t)i*32;
  float pv=0.f, rv=0.f;
  #pragma unroll
  for (int c=0;c<32;++c){
    float mu = stats[c]*invn;
    float var = stats[32+c]*invn - mu*mu;
    float rsd = 1.0f / sqrtf(var + 1e-5f);
    float v = (hp[c]-mu)*rsd*g[c] + be[c];
    v = lrelu(v);
    hp[c] = v;
    pv += v*Wr[c];
    rv += v*Wroot[c];
  }
  p[i] = pv;
  s[i] = rv + br[0];
}

// ---------------- final: select top-k2, pooled += h2p * tanh(s2) ----------------
__global__ __launch_bounds__(TPB) void k_final(
    const unsigned* __restrict__ ukey, const float* __restrict__ s2,
    const float* __restrict__ h2p, unsigned* __restrict__ ctrl,
    float* __restrict__ pooled, int N)
{
  __shared__ float red[TPB][33];
  int i = blockIdx.x*TPB + threadIdx.x;
  float contrib[32];
  #pragma unroll
  for (int c=0;c<32;++c) contrib[c]=0.f;
  if (i < N){
    unsigned u = ukey[i], T = ctrl[3], needT = ctrl[4];
    bool sel = u > T;
    if (!sel && u == T) sel = (atomicAdd(&ctrl[5], 1u) < needT);
    if (sel){
      float tv = tanhf(s2[i]);
      const float* hp = h2p + (size_t)i*32;
      #pragma unroll
      for (int c=0;c<32;++c) contrib[c] = hp[c]*tv;
    }
  }
  #pragma unroll
  for (int c=0;c<32;++c) red[threadIdx.x][c]=contrib[c];
  __syncthreads();
  if (threadIdx.x < 64){
    int c = threadIdx.x & 31, r0 = (threadIdx.x>>5)*128;
    float sm=0.f;
    for (int r=0;r<128;++r) sm += red[r0+r][c];
    atomicAdd(&pooled[c], sm);
  }
}

// ---------------- tiny MLP 32->8->4->2 ----------------
__global__ void k_mlp(const float* __restrict__ pooled,
    const float* __restrict__ fw1, const float* __restrict__ fb1,
    const float* __restrict__ fw2, const float* __restrict__ fb2,
    const float* __restrict__ fw3, const float* __restrict__ fb3,
    float* __restrict__ out)
{
  if (blockIdx.x==0 && threadIdx.x==0){
    float a[8];
    for (int o=0;o<8;++o){
      float t = fb1[o];
      for (int c=0;c<32;++c) t += pooled[c]*fw1[c*8+o];
      a[o] = lrelu(t);
    }
    float b[4];
    for (int o=0;o<4;++o){
      float t = fb2[o];
      for (int c=0;c<8;++c) t += a[c]*fw2[c*4+o];
      b[o] = lrelu(t);
    }
    for (int o=0;o<2;++o){
      float t = fb3[o];
      for (int c=0;c<4;++c) t += b[c]*fw3[c*2+o];
      out[o] = lrelu(t);
    }
  }
}

extern "C" void kernel_launch(void* const* d_in, const int* in_sizes, int n_in,
                              void* d_out, int out_size, void* d_ws, size_t ws_size,
                              hipStream_t stream)
{
  const float* x      = (const float*)d_in[0];
  const int*   ei     = (const int*)  d_in[1];
  // d_in[2] edge_weigth, d_in[3] batch: unused by the reference math
  const float* W1     = (const float*)d_in[4];
  const float* g1     = (const float*)d_in[6];
  const float* be1    = (const float*)d_in[7];
  const float* Wr1    = (const float*)d_in[8];
  const float* br1    = (const float*)d_in[9];
  const float* Wroot1 = (const float*)d_in[10];
  const float* W2     = (const float*)d_in[11];
  const float* g2     = (const float*)d_in[13];
  const float* be2    = (const float*)d_in[14];
  const float* Wr2    = (const float*)d_in[15];
  const float* br2    = (const float*)d_in[16];
  const float* Wroot2 = (const float*)d_in[17];
  const float* fw1    = (const float*)d_in[18];
  const float* fb1    = (const float*)d_in[19];
  const float* fw2    = (const float*)d_in[20];
  const float* fb2    = (const float*)d_in[21];
  const float* fw3    = (const float*)d_in[22];
  const float* fb3    = (const float*)d_in[23];

  int N = in_sizes[0] / 128;
  int E = in_sizes[1] / 2;
  const int* srcp = ei;
  const int* dstp = ei + E;
  int k1 = (N + 1) / 2;
  int k2 = (k1 + 1) / 2;

  char* w = (char*)d_ws;
  size_t off = 0;
  auto alloc = [&](size_t bytes)->char* {
    char* ptr = w + off;
    off += (bytes + 255) & ~(size_t)255;
    return ptr;
  };
  // --- zeroed prefix: cnt | hist | ctrl(+stats+pooled) ---
  int*      cnt  = (int*)     alloc((size_t)N*4);
  unsigned* hist = (unsigned*)alloc(65536*4);
  unsigned* ctrl = (unsigned*)alloc(1024);
  size_t zerosz = off;
  float* stats1 = (float*)(ctrl + 32);   // 32 floats
  float* stats2 = (float*)(ctrl + 96);   // 64 floats
  float* pooled = (float*)(ctrl + 160);  // 32 floats
  // --- rest of workspace ---
  int*      row_start = (int*)     alloc((size_t)N*4);
  int*      cursor    = (int*)     alloc((size_t)N*4);
  int*      col       = (int*)     alloc((size_t)E*4);
  float*    h1        = (float*)   alloc((size_t)N*16*4); // later reused as z1
  float*    agg1      = (float*)   alloc((size_t)N*16*4); // later h1p (in place)
  float*    h2        = (float*)   alloc((size_t)N*32*4); // later h2p (in place)
  float*    sbuf      = (float*)   alloc((size_t)N*4);    // s1 then s2
  float*    pbuf      = (float*)   alloc((size_t)N*4);    // p1 then p2
  unsigned* ukey      = (unsigned*)alloc((size_t)N*4);
  unsigned char* keep = (unsigned char*)alloc((size_t)N);
  unsigned* cand      = (unsigned*)alloc((size_t)CAND_CAP*4);
  (void)ws_size; (void)n_in; (void)out_size;

  int nbN = (N + TPB - 1) / TPB;

  hipMemsetAsync(d_ws, 0, zerosz, stream);

  // layer 1
  k_gemm1_hist<<<(N + 1023)/1024, TPB, 0, stream>>>(x, W1, h1, N, dstp, E, cnt);
  k_alloc     <<<nbN, TPB, 0, stream>>>(cnt, row_start, cursor, N, ctrl);
  k_scatter   <<<(E + TPB - 1)/TPB, TPB, 0, stream>>>(srcp, dstp, E, cursor, col);
  k_conv1agg  <<<nbN, TPB, 0, stream>>>(h1, row_start, cursor, col, agg1, N, stats1);
  k_bn1       <<<nbN, TPB, 0, stream>>>(agg1, stats1, g1, be1, Wr1, br1, Wroot1,
                                        pbuf, sbuf, N, 1.0f/(float)N);
  k_scoreagg  <<<nbN, TPB, 0, stream>>>(pbuf, row_start, cursor, col, sbuf, nullptr, N);
  // SAG pool 1 (radix select k1)
  k_keyhist   <<<nbN, TPB, 0, stream>>>(sbuf, nullptr, ukey, hist, N);
  k_findbucket<<<1, TPB, 0, stream>>>(hist, (unsigned)k1, ctrl);
  k_collect   <<<nbN, TPB, 0, stream>>>(ukey, cand, ctrl, hist, N);
  k_refine    <<<1, TPB, 0, stream>>>(cand, ctrl);
  k_mark1     <<<nbN, TPB, 0, stream>>>(ukey, sbuf, agg1, h1, keep, ctrl, N);
  // layer 2
  k_conv2     <<<nbN, TPB, 0, stream>>>(h1, row_start, cursor, col, keep, W2, h2, N, stats2);
  k_bn2       <<<nbN, TPB, 0, stream>>>(h2, stats2, g2, be2, Wr2, br2, Wroot2, keep,
                                        pbuf, sbuf, N, 1.0f/(float)k1);
  k_scoreagg  <<<nbN, TPB, 0, stream>>>(pbuf, row_start, cursor, col, sbuf, keep, N);
  // SAG pool 2 (radix select k2) + global pool
  k_keyhist   <<<nbN, TPB, 0, stream>>>(sbuf, keep, ukey, hist, N);
  k_findbucket<<<1, TPB, 0, stream>>>(hist, (unsigned)k2, ctrl);
  k_collect   <<<nbN, TPB, 0, stream>>>(ukey, cand, ctrl, hist, N);
  k_refine    <<<1, TPB, 0, stream>>>(cand, ctrl);
  k_final     <<<nbN, TPB, 0, stream>>>(ukey, sbuf, h2, ctrl, pooled, N);
  k_mlp       <<<1, 64, 0, stream>>>(pooled, fw1, fb1, fw2, fb2, fw3, fb3, (float*)d_out);
}

// Round 2
// 1969.646 us; speedup vs baseline: 1.0262x; 1.0262x over previous
//
#include <hip/hip_runtime.h>
#include <math.h>

#define TPB 256
#define CAND_CAP 262144u
#define BSH 8          // bucket = dst >> 8  (256 dst per bucket)
#define BCAP 10240     // slots per bucket: Poisson mean 8190, +22 sigma
#define MAXB 1024      // LDS histogram capacity (N <= 262144)
#define BIN_BLOCKS 1024

__device__ __forceinline__ float lrelu(float v){ return v >= 0.0f ? v : 0.01f*v; }
__device__ __forceinline__ unsigned fkey(float f){
  unsigned b = __float_as_uint(f);
  return (b & 0x80000000u) ? ~b : (b | 0x80000000u);
}

// ---------------- gemm1: h1 = x @ W1 (128->16) ----------------
__global__ __launch_bounds__(TPB) void k_gemm1(
    const float* __restrict__ x, const float* __restrict__ W1,
    float* __restrict__ h1, int N)
{
  __shared__ float Ws[2048]; // transposed: Ws[c*128+k]
  for (int idx = threadIdx.x; idx < 2048; idx += TPB){
    int k = idx >> 4, c = idx & 15;
    Ws[c*128 + k] = W1[idx];
  }
  __syncthreads();
  int base = blockIdx.x*(2*TPB) + threadIdx.x;
  int nn[2]; bool val[2];
  #pragma unroll
  for (int j=0;j<2;++j){ nn[j] = base + j*TPB; val[j] = nn[j] < N; }
  float acc[2][16];
  #pragma unroll
  for (int j=0;j<2;++j)
    #pragma unroll
    for (int c=0;c<16;++c) acc[j][c]=0.f;
  for (int k4=0;k4<32;++k4){
    float4 xv[2];
    #pragma unroll
    for (int j=0;j<2;++j)
      xv[j] = val[j] ? ((const float4*)(x + (size_t)nn[j]*128))[k4] : make_float4(0.f,0.f,0.f,0.f);
    #pragma unroll
    for (int c=0;c<16;++c){
      float4 wv = *(const float4*)&Ws[c*128 + k4*4];
      #pragma unroll
      for (int j=0;j<2;++j)
        acc[j][c] += xv[j].x*wv.x + xv[j].y*wv.y + xv[j].z*wv.z + xv[j].w*wv.w;
    }
  }
  #pragma unroll
  for (int j=0;j<2;++j) if (val[j]){
    float4* op = (float4*)(h1 + (size_t)nn[j]*16);
    #pragma unroll
    for (int q=0;q<4;++q)
      op[q] = make_float4(acc[j][q*4+0],acc[j][q*4+1],acc[j][q*4+2],acc[j][q*4+3]);
  }
}

// ---------------- bin edges into coarse buckets (dst>>8), packed (dstlow<<24)|src ----------
__global__ __launch_bounds__(TPB) void k_bin(
    const int* __restrict__ src, const int* __restrict__ dst, int E,
    int* __restrict__ gcur, unsigned* __restrict__ col)
{
  __shared__ int histL[MAXB];
  int chunk = (E + BIN_BLOCKS - 1) / BIN_BLOCKS;
  int e0 = blockIdx.x * chunk;
  int e1 = e0 + chunk; if (e1 > E) e1 = E;
  for (int i = threadIdx.x; i < MAXB; i += TPB) histL[i] = 0;
  __syncthreads();
  for (int e = e0 + threadIdx.x; e < e1; e += TPB)
    atomicAdd(&histL[dst[e] >> BSH], 1);
  __syncthreads();
  for (int b = threadIdx.x; b < MAXB; b += TPB){
    int c = histL[b];
    histL[b] = (c > 0) ? atomicAdd(&gcur[b], c) : 0;
  }
  __syncthreads();
  for (int e = e0 + threadIdx.x; e < e1; e += TPB){
    int d = dst[e];
    int b = d >> BSH;
    int slot = atomicAdd(&histL[b], 1);
    if (slot < BCAP)
      col[(size_t)b * BCAP + slot] = ((unsigned)(d & 255) << 24) | (unsigned)src[e];
  }
}

// ---------------- conv1 aggregation: one block per bucket, LDS accumulate + BN stats --------
__global__ __launch_bounds__(TPB) void k_conv1agg(
    const float* __restrict__ h1, const unsigned* __restrict__ col,
    const int* __restrict__ gcur, float* __restrict__ agg, int N,
    float* __restrict__ stats)
{
  __shared__ float acc[16*256]; // acc[c*256 + dstlow] : bank = dstlow&31
  int b = blockIdx.x;
  for (int i = threadIdx.x; i < 4096; i += TPB) acc[i] = 0.f;
  __syncthreads();
  int len = gcur[b]; if (len > BCAP) len = BCAP;
  const unsigned* ce = col + (size_t)b * BCAP;
  for (int e = threadIdx.x; e < len; e += TPB){
    unsigned pk = ce[e];
    int s  = (int)(pk & 0xFFFFFFu);
    int dl = (int)(pk >> 24);
    const float4* hp = (const float4*)(h1 + (size_t)s * 16);
    float4 v0=hp[0], v1=hp[1], v2=hp[2], v3=hp[3];
    atomicAdd(&acc[ 0*256+dl], v0.x); atomicAdd(&acc[ 1*256+dl], v0.y);
    atomicAdd(&acc[ 2*256+dl], v0.z); atomicAdd(&acc[ 3*256+dl], v0.w);
    atomicAdd(&acc[ 4*256+dl], v1.x); atomicAdd(&acc[ 5*256+dl], v1.y);
    atomicAdd(&acc[ 6*256+dl], v1.z); atomicAdd(&acc[ 7*256+dl], v1.w);
    atomicAdd(&acc[ 8*256+dl], v2.x); atomicAdd(&acc[ 9*256+dl], v2.y);
    atomicAdd(&acc[10*256+dl], v2.z); atomicAdd(&acc[11*256+dl], v2.w);
    atomicAdd(&acc[12*256+dl], v3.x); atomicAdd(&acc[13*256+dl], v3.y);
    atomicAdd(&acc[14*256+dl], v3.z); atomicAdd(&acc[15*256+dl], v3.w);
  }
  __syncthreads();
  int t = threadIdx.x;
  int d = b*256 + t;
  if (d < N){
    float4* op = (float4*)(agg + (size_t)d * 16);
    #pragma unroll
    for (int q=0;q<4;++q)
      op[q] = make_float4(acc[(q*4+0)*256+t], acc[(q*4+1)*256+t],
                          acc[(q*4+2)*256+t], acc[(q*4+3)*256+t]);
  }
  if (t < 32){
    int c = t & 15, r0 = (t>>4)*128;
    float sm=0.f, q=0.f;
    for (int r=0;r<128;++r){ float v = acc[c*256 + r0 + r]; sm+=v; q+=v*v; }
    atomicAdd(&stats[c], sm);
    atomicAdd(&stats[16+c], q);
  }
}

// ---------------- BN1 + lrelu (in place) + p1 = h.Wrel, s1 = h.Wroot + br ----------------
__global__ __launch_bounds__(TPB) void k_bn1(
    float* __restrict__ h, const float* __restrict__ stats,
    const float* __restrict__ g, const float* __restrict__ be,
    const float* __restrict__ Wr, const float* __restrict__ br,
    const float* __restrict__ Wroot,
    float* __restrict__ p, float* __restrict__ s, int N, float invn)
{
  int i = blockIdx.x*TPB + threadIdx.x;
  if (i >= N) return;
  float* hp = h + (size_t)i*16;
  float pv=0.f, rv=0.f;
  #pragma unroll
  for (int c=0;c<16;++c){
    float mu = stats[c]*invn;
    float var = stats[16+c]*invn - mu*mu;
    float rsd = 1.0f / sqrtf(var + 1e-5f);
    float v = (hp[c]-mu)*rsd*g[c] + be[c];
    v = lrelu(v);
    hp[c] = v;
    pv += v*Wr[c];
    rv += v*Wroot[c];
  }
  p[i] = pv;
  s[i] = rv + br[0];
}

// ---------------- score aggregation: s[d] += sum p[src], one block per bucket --------------
// layer 2 needs no mask: bn2 zeroes p for dropped nodes; dropped dst rows are masked later.
__global__ __launch_bounds__(TPB) void k_score(
    const float* __restrict__ p, const unsigned* __restrict__ col,
    const int* __restrict__ gcur, float* __restrict__ s, int N)
{
  __shared__ float sacc[256];
  int b = blockIdx.x;
  sacc[threadIdx.x] = 0.f;
  __syncthreads();
  int len = gcur[b]; if (len > BCAP) len = BCAP;
  const unsigned* ce = col + (size_t)b * BCAP;
  for (int e = threadIdx.x; e < len; e += TPB){
    unsigned pk = ce[e];
    atomicAdd(&sacc[pk >> 24], p[pk & 0xFFFFFFu]);
  }
  __syncthreads();
  int d = b*256 + threadIdx.x;
  if (d < N) s[d] += sacc[threadIdx.x];
}

// ---------------- radix-select stage 1: monotonic keys + top-16-bit histogram ----------------
__global__ __launch_bounds__(TPB) void k_keyhist(
    const float* __restrict__ s, const unsigned char* __restrict__ keep,
    unsigned* __restrict__ ukey, unsigned* __restrict__ hist, int N)
{
  int i = blockIdx.x*TPB + threadIdx.x;
  if (i >= N) return;
  unsigned u = 0u;
  if (!keep || keep[i]) u = fkey(s[i]);
  ukey[i] = u;
  if (u) atomicAdd(&hist[u>>16], 1u);
}

// ---------------- find threshold bucket (1 block) ----------------
__global__ __launch_bounds__(TPB) void k_findbucket(
    const unsigned* __restrict__ hist, unsigned k, unsigned* __restrict__ ctrl)
{
  __shared__ unsigned seg[TPB];
  __shared__ unsigned hb[256];
  __shared__ unsigned sS, scum;
  unsigned t = threadIdx.x;
  const uint4* h4 = (const uint4*)hist;
  unsigned ssum = 0;
  for (int q=0;q<64;++q){
    uint4 v = h4[t*64 + q];
    ssum += v.x + v.y + v.z + v.w;
  }
  seg[t] = ssum;
  __syncthreads();
  if (t == 0){
    unsigned cum = 0, S = 255;
    for (int s2=255; s2>=0; --s2){
      if (cum + seg[s2] >= k){ S = (unsigned)s2; break; }
      cum += seg[s2];
    }
    sS = S; scum = cum;
  }
  __syncthreads();
  hb[t] = hist[sS*256 + t];
  __syncthreads();
  if (t == 0){
    unsigned cum = scum, B = 0, need = 0;
    for (int b=255;b>=0;--b){
      unsigned h = hb[b];
      if (cum + h >= k){ B = sS*256 + (unsigned)b; need = k - cum; break; }
      cum += h;
    }
    ctrl[1] = B;
    ctrl[2] = need;
  }
}

// ---------------- collect boundary-bucket candidates; also re-zero hist for next use --------
__global__ __launch_bounds__(TPB) void k_collect(
    const unsigned* __restrict__ ukey, unsigned* __restrict__ cand,
    unsigned* __restrict__ ctrl, unsigned* __restrict__ hist, int N)
{
  int i = blockIdx.x*TPB + threadIdx.x;
  if (i < 65536) hist[i] = 0u;
  if (i < N){
    unsigned u = ukey[i];
    if ((u>>16) == ctrl[1]){
      unsigned pos = atomicAdd(&ctrl[6], 1u);
      if (pos < CAND_CAP) cand[pos] = u;
    }
  }
}

// ---------------- refine low 16 bits (1 block) -> T, needT; resets tie & cand counters ------
__global__ __launch_bounds__(TPB) void k_refine(
    const unsigned* __restrict__ cand, unsigned* __restrict__ ctrl)
{
  __shared__ unsigned h8[256];
  __shared__ unsigned sB2, sN2;
  unsigned t = threadIdx.x;
  unsigned L = ctrl[6];
  unsigned need = ctrl[2];
  h8[t] = 0u; __syncthreads();
  for (unsigned i=t; i<L; i+=TPB) atomicAdd(&h8[(cand[i]>>8)&0xFFu], 1u);
  __syncthreads();
  if (t == 0){
    unsigned cum=0, B2=0, n2=need;
    for (int b=255;b>=0;--b){
      unsigned h = h8[b];
      if (cum + h >= need){ B2=(unsigned)b; n2 = need - cum; break; }
      cum += h;
    }
    sB2 = B2; sN2 = n2;
  }
  __syncthreads();
  unsigned B2 = sB2, need2 = sN2;
  h8[t] = 0u; __syncthreads();
  for (unsigned i=t; i<L; i+=TPB){
    unsigned u = cand[i];
    if (((u>>8)&0xFFu) == B2) atomicAdd(&h8[u&0xFFu], 1u);
  }
  __syncthreads();
  if (t == 0){
    unsigned cum=0, B3=0, n3=need2;
    for (int b=255;b>=0;--b){
      unsigned h = h8[b];
      if (cum + h >= need2){ B3=(unsigned)b; n3 = need2 - cum; break; }
      cum += h;
    }
    unsigned B = ctrl[1];
    ctrl[3] = (B<<16) | (B2<<8) | B3; // threshold key T
    ctrl[4] = n3;                    // how many ==T to take
    ctrl[5] = 0u;                    // tie counter
    ctrl[6] = 0u;                    // cand counter (for next selection)
  }
}

// ---------------- mark keep1 + z1 = keep ? h1p * tanh(s1) : 0 ----------------
__global__ __launch_bounds__(TPB) void k_mark1(
    const unsigned* __restrict__ ukey, const float* __restrict__ s1,
    const float* __restrict__ h1p, float* __restrict__ z1,
    unsigned char* __restrict__ keep, unsigned* __restrict__ ctrl, int N)
{
  int i = blockIdx.x*TPB + threadIdx.x;
  if (i >= N) return;
  unsigned u = ukey[i], T = ctrl[3], needT = ctrl[4];
  bool sel = u > T;
  if (!sel && u == T) sel = (atomicAdd(&ctrl[5], 1u) < needT);
  keep[i] = sel ? (unsigned char)1 : (unsigned char)0;
  float tv = sel ? tanhf(s1[i]) : 0.0f;
  const float4* hp = (const float4*)(h1p + (size_t)i*16);
  float4* zp = (float4*)(z1 + (size_t)i*16);
  #pragma unroll
  for (int q=0;q<4;++q){
    float4 v = hp[q];
    zp[q] = make_float4(v.x*tv, v.y*tv, v.z*tv, v.w*tv);
  }
}

// ---------------- conv2: bucketed masked aggregation + GEMM 16->32 + BN stats ----------
__global__ __launch_bounds__(TPB) void k_conv2(
    const float* __restrict__ z1, const unsigned* __restrict__ col,
    const int* __restrict__ gcur, const unsigned char* __restrict__ keep,
    const float* __restrict__ W2, float* __restrict__ h2, int N,
    float* __restrict__ stats)
{
  __shared__ float acc[16*256];
  __shared__ float W2s[512];
  __shared__ float red[TPB][33];
  for (int i = threadIdx.x; i < 4096; i += TPB) acc[i] = 0.f;
  for (int i = threadIdx.x; i < 512; i += TPB) W2s[i] = W2[i];
  __syncthreads();
  int b = blockIdx.x;
  int len = gcur[b]; if (len > BCAP) len = BCAP;
  const unsigned* ce = col + (size_t)b * BCAP;
  for (int e = threadIdx.x; e < len; e += TPB){
    unsigned pk = ce[e];
    int s = (int)(pk & 0xFFFFFFu);
    if (!keep[s]) continue;   // z1[s]==0 anyway; skip the 64B gather
    int dl = (int)(pk >> 24);
    const float4* zp = (const float4*)(z1 + (size_t)s * 16);
    float4 v0=zp[0], v1=zp[1], v2=zp[2], v3=zp[3];
    atomicAdd(&acc[ 0*256+dl], v0.x); atomicAdd(&acc[ 1*256+dl], v0.y);
    atomicAdd(&acc[ 2*256+dl], v0.z); atomicAdd(&acc[ 3*256+dl], v0.w);
    atomicAdd(&acc[ 4*256+dl], v1.x); atomicAdd(&acc[ 5*256+dl], v1.y);
    atomicAdd(&acc[ 6*256+dl], v1.z); atomicAdd(&acc[ 7*256+dl], v1.w);
    atomicAdd(&acc[ 8*256+dl], v2.x); atomicAdd(&acc[ 9*256+dl], v2.y);
    atomicAdd(&acc[10*256+dl], v2.z); atomicAdd(&acc[11*256+dl], v2.w);
    atomicAdd(&acc[12*256+dl], v3.x); atomicAdd(&acc[13*256+dl], v3.y);
    atomicAdd(&acc[14*256+dl], v3.z); atomicAdd(&acc[15*256+dl], v3.w);
  }
  __syncthreads();
  int t = threadIdx.x;
  int d = b*256 + t;
  float h[32];
  #pragma unroll
  for (int c2=0;c2<32;++c2) h[c2]=0.f;
  bool act = (d < N) && keep[d];
  if (act){
    #pragma unroll
    for (int c=0;c<16;++c){
      float av = acc[c*256 + t];
      const float* wrow = &W2s[c*32];
      #pragma unroll
      for (int c2=0;c2<32;++c2) h[c2] += av*wrow[c2];
    }
    float4* op = (float4*)(h2 + (size_t)d*32);
    #pragma unroll
    for (int q=0;q<8;++q)
      op[q] = make_float4(h[q*4+0],h[q*4+1],h[q*4+2],h[q*4+3]);
  }
  #pragma unroll
  for (int c2=0;c2<32;++c2) red[t][c2]=h[c2];
  __syncthreads();
  if (t < 64){
    int c = t & 31, r0 = (t>>5)*128;
    float sm=0.f, q=0.f;
    for (int r=0;r<128;++r){ float v = red[r0+r][c]; sm+=v; q+=v*v; }
    atomicAdd(&stats[c], sm);
    atomicAdd(&stats[32+c], q);
  }
}

// ---------------- BN2 + lrelu (kept rows) + p2, s2; zero p/s for dropped ----------------
__global__ __launch_bounds__(TPB) void k_bn2(
    float* __restrict__ h, const float* __restrict__ stats,
    const float* __restrict__ g, const float* __restrict__ be,
    const float* __restrict__ Wr, const float* __restrict__ br,
    const float* __restrict__ Wroot, const unsigned char* __restrict__ keep,
    float* __restrict__ p, float* __restrict__ s, int N, float invn)
{
  int i = blockIdx.x*TPB + threadIdx.x;
  if (i >= N) return;
  if (!keep[i]){ p[i] = 0.f; s[i] = 0.f; return; }
  float* hp = h + (size_t)i*32;
  float pv=0.f, rv=0.f;
  #pragma unroll
  for (int c=0;c<32;++c){
    float mu = stats[c]*invn;
    float var = stats[32+c]*invn - mu*mu;
    float rsd = 1.0f / sqrtf(var + 1e-5f);
    float v = (hp[c]-mu)*rsd*g[c] + be[c];
    v = lrelu(v);
    hp[c] = v;
    pv += v*Wr[c];
    rv += v*Wroot[c];
  }
  p[i] = pv;
  s[i] = rv + br[0];
}

// ---------------- final: select top-k2, pooled += h2p * tanh(s2) ----------------
__global__ __launch_bounds__(TPB) void k_final(
    const unsigned* __restrict__ ukey, const float* __restrict__ s2,
    const float* __restrict__ h2p, unsigned* __restrict__ ctrl,
    float* __restrict__ pooled, int N)
{
  __shared__ float red[TPB][33];
  int i = blockIdx.x*TPB + threadIdx.x;
  float contrib[32];
  #pragma unroll
  for (int c=0;c<32;++c) contrib[c]=0.f;
  if (i < N){
    unsigned u = ukey[i], T = ctrl[3], needT = ctrl[4];
    bool sel = u > T;
    if (!sel && u == T) sel = (atomicAdd(&ctrl[5], 1u) < needT);
    if (sel){
      float tv = tanhf(s2[i]);
      const float* hp = h2p + (size_t)i*32;
      #pragma unroll
      for (int c=0;c<32;++c) contrib[c] = hp[c]*tv;
    }
  }
  #pragma unroll
  for (int c=0;c<32;++c) red[threadIdx.x][c]=contrib[c];
  __syncthreads();
  if (threadIdx.x < 64){
    int c = threadIdx.x & 31, r0 = (threadIdx.x>>5)*128;
    float sm=0.f;
    for (int r=0;r<128;++r) sm += red[r0+r][c];
    atomicAdd(&pooled[c], sm);
  }
}

// ---------------- tiny MLP 32->8->4->2 ----------------
__global__ void k_mlp(const float* __restrict__ pooled,
    const float* __restrict__ fw1, const float* __restrict__ fb1,
    const float* __restrict__ fw2, const float* __restrict__ fb2,
    const float* __restrict__ fw3, const float* __restrict__ fb3,
    float* __restrict__ out)
{
  if (blockIdx.x==0 && threadIdx.x==0){
    float a[8];
    for (int o=0;o<8;++o){
      float t = fb1[o];
      for (int c=0;c<32;++c) t += pooled[c]*fw1[c*8+o];
      a[o] = lrelu(t);
    }
    float b[4];
    for (int o=0;o<4;++o){
      float t = fb2[o];
      for (int c=0;c<8;++c) t += a[c]*fw2[c*4+o];
      b[o] = lrelu(t);
    }
    for (int o=0;o<2;++o){
      float t = fb3[o];
      for (int c=0;c<4;++c) t += b[c]*fw3[c*2+o];
      out[o] = lrelu(t);
    }
  }
}

extern "C" void kernel_launch(void* const* d_in, const int* in_sizes, int n_in,
                              void* d_out, int out_size, void* d_ws, size_t ws_size,
                              hipStream_t stream)
{
  const float* x      = (const float*)d_in[0];
  const int*   ei     = (const int*)  d_in[1];
  // d_in[2] edge_weigth, d_in[3] batch: unused by the reference math
  const float* W1     = (const float*)d_in[4];
  const float* g1     = (const float*)d_in[6];
  const float* be1    = (const float*)d_in[7];
  const float* Wr1    = (const float*)d_in[8];
  const float* br1    = (const float*)d_in[9];
  const float* Wroot1 = (const float*)d_in[10];
  const float* W2     = (const float*)d_in[11];
  const float* g2     = (const float*)d_in[13];
  const float* be2    = (const float*)d_in[14];
  const float* Wr2    = (const float*)d_in[15];
  const float* br2    = (const float*)d_in[16];
  const float* Wroot2 = (const float*)d_in[17];
  const float* fw1    = (const float*)d_in[18];
  const float* fb1    = (const float*)d_in[19];
  const float* fw2    = (const float*)d_in[20];
  const float* fb2    = (const float*)d_in[21];
  const float* fw3    = (const float*)d_in[22];
  const float* fb3    = (const float*)d_in[23];

  int N = in_sizes[0] / 128;
  int E = in_sizes[1] / 2;
  const int* srcp = ei;
  const int* dstp = ei + E;
  int k1 = (N + 1) / 2;
  int k2 = (k1 + 1) / 2;
  int NB  = (N + 255) >> 8;           // number of coarse buckets (<= MAXB)
  int nbN = (N + TPB - 1) / TPB;

  char* w = (char*)d_ws;
  size_t off = 0;
  auto alloc = [&](size_t bytes)->char* {
    char* ptr = w + off;
    off += (bytes + 255) & ~(size_t)255;
    return ptr;
  };
  // --- zeroed prefix: gcur | hist | ctrl(+stats+pooled) ---
  int*      gcur = (int*)     alloc((size_t)MAXB*4);
  unsigned* hist = (unsigned*)alloc(65536*4);
  unsigned* ctrl = (unsigned*)alloc(1024);
  size_t zerosz = off;
  float* stats1 = (float*)(ctrl + 32);   // 32 floats
  float* stats2 = (float*)(ctrl + 96);   // 64 floats
  float* pooled = (float*)(ctrl + 160);  // 32 floats
  // --- rest of workspace ---
  unsigned* col  = (unsigned*)alloc((size_t)NB*BCAP*4);
  float*    h1   = (float*)   alloc((size_t)N*16*4); // later reused as z1
  float*    agg1 = (float*)   alloc((size_t)N*16*4); // later h1p (in place)
  float*    h2   = (float*)   alloc((size_t)N*32*4); // later h2p (in place)
  float*    sbuf = (float*)   alloc((size_t)N*4);    // s1 then s2
  float*    pbuf = (float*)   alloc((size_t)N*4);    // p1 then p2
  unsigned* ukey = (unsigned*)alloc((size_t)N*4);
  unsigned char* keep = (unsigned char*)alloc((size_t)N);
  unsigned* cand = (unsigned*)alloc((size_t)CAND_CAP*4);
  (void)ws_size; (void)n_in; (void)out_size;

  hipMemsetAsync(d_ws, 0, zerosz, stream);

  // layer 1
  k_gemm1     <<<(N + 2*TPB - 1)/(2*TPB), TPB, 0, stream>>>(x, W1, h1, N);
  k_bin       <<<BIN_BLOCKS, TPB, 0, stream>>>(srcp, dstp, E, gcur, col);
  k_conv1agg  <<<NB, TPB, 0, stream>>>(h1, col, gcur, agg1, N, stats1);
  k_bn1       <<<nbN, TPB, 0, stream>>>(agg1, stats1, g1, be1, Wr1, br1, Wroot1,
                                        pbuf, sbuf, N, 1.0f/(float)N);
  k_score     <<<NB, TPB, 0, stream>>>(pbuf, col, gcur, sbuf, N);
  // SAG pool 1 (radix select k1)
  k_keyhist   <<<nbN, TPB, 0, stream>>>(sbuf, nullptr, ukey, hist, N);
  k_findbucket<<<1, TPB, 0, stream>>>(hist, (unsigned)k1, ctrl);
  k_collect   <<<nbN, TPB, 0, stream>>>(ukey, cand, ctrl, hist, N);
  k_refine    <<<1, TPB, 0, stream>>>(cand, ctrl);
  k_mark1     <<<nbN, TPB, 0, stream>>>(ukey, sbuf, agg1, h1, keep, ctrl, N);
  // layer 2
  k_conv2     <<<NB, TPB, 0, stream>>>(h1, col, gcur, keep, W2, h2, N, stats2);
  k_bn2       <<<nbN, TPB, 0, stream>>>(h2, stats2, g2, be2, Wr2, br2, Wroot2, keep,
                                        pbuf, sbuf, N, 1.0f/(float)k1);
  k_score     <<<NB, TPB, 0, stream>>>(pbuf, col, gcur, sbuf, N);
  // SAG pool 2 (radix select k2) + global pool
  k_keyhist   <<<nbN, TPB, 0, stream>>>(sbuf, keep, ukey, hist, N);
  k_findbucket<<<1, TPB, 0, stream>>>(hist, (unsigned)k2, ctrl);
  k_collect   <<<nbN, TPB, 0, stream>>>(ukey, cand, ctrl, hist, N);
  k_refine    <<<1, TPB, 0, stream>>>(cand, ctrl);
  k_final     <<<nbN, TPB, 0, stream>>>(ukey, sbuf, h2, ctrl, pooled, N);
  k_mlp       <<<1, 64, 0, stream>>>(pooled, fw1, fb1, fw2, fb2, fw3, fb3, (float*)d_out);
}

// Round 3
// 1872.026 us; speedup vs baseline: 1.0797x; 1.0521x over previous
//
#include <hip/hip_runtime.h>
#include <math.h>

#define TPB 256
#define CAND_CAP 262144u
#define BSH 7          // bucket = dst >> 7  (128 dst per bucket)
#define BBW 128        // dsts per bucket
#define BCAP 5120      // slots per bucket: mean 4096, +16 sigma
#define MAXB 2048      // LDS histogram capacity (N <= 262144)
#define BIN_BLOCKS 512

__device__ __forceinline__ float lrelu(float v){ return v >= 0.0f ? v : 0.01f*v; }
__device__ __forceinline__ unsigned fkey(float f){
  unsigned b = __float_as_uint(f);
  return (b & 0x80000000u) ? ~b : (b | 0x80000000u);
}

// ---------------- gemm1: h1 = x @ W1 (128->16) ----------------
__global__ __launch_bounds__(TPB) void k_gemm1(
    const float* __restrict__ x, const float* __restrict__ W1,
    float* __restrict__ h1, int N)
{
  __shared__ float Ws[2048]; // transposed: Ws[c*128+k]
  for (int idx = threadIdx.x; idx < 2048; idx += TPB){
    int k = idx >> 4, c = idx & 15;
    Ws[c*128 + k] = W1[idx];
  }
  __syncthreads();
  int base = blockIdx.x*(2*TPB) + threadIdx.x;
  int nn[2]; bool val[2];
  #pragma unroll
  for (int j=0;j<2;++j){ nn[j] = base + j*TPB; val[j] = nn[j] < N; }
  float acc[2][16];
  #pragma unroll
  for (int j=0;j<2;++j)
    #pragma unroll
    for (int c=0;c<16;++c) acc[j][c]=0.f;
  for (int k4=0;k4<32;++k4){
    float4 xv[2];
    #pragma unroll
    for (int j=0;j<2;++j)
      xv[j] = val[j] ? ((const float4*)(x + (size_t)nn[j]*128))[k4] : make_float4(0.f,0.f,0.f,0.f);
    #pragma unroll
    for (int c=0;c<16;++c){
      float4 wv = *(const float4*)&Ws[c*128 + k4*4];
      #pragma unroll
      for (int j=0;j<2;++j)
        acc[j][c] += xv[j].x*wv.x + xv[j].y*wv.y + xv[j].z*wv.z + xv[j].w*wv.w;
    }
  }
  #pragma unroll
  for (int j=0;j<2;++j) if (val[j]){
    float4* op = (float4*)(h1 + (size_t)nn[j]*16);
    #pragma unroll
    for (int q=0;q<4;++q)
      op[q] = make_float4(acc[j][q*4+0],acc[j][q*4+1],acc[j][q*4+2],acc[j][q*4+3]);
  }
}

// ---------------- bin edges into buckets (dst>>7), packed (dst&127)<<24 | src ----------
__global__ __launch_bounds__(TPB) void k_bin(
    const int* __restrict__ src, const int* __restrict__ dst, int E,
    int* __restrict__ gcur, unsigned* __restrict__ col)
{
  __shared__ int histL[MAXB];
  int chunk = (E + BIN_BLOCKS - 1) / BIN_BLOCKS;
  int e0 = blockIdx.x * chunk;
  int e1 = e0 + chunk; if (e1 > E) e1 = E;
  for (int i = threadIdx.x; i < MAXB; i += TPB) histL[i] = 0;
  __syncthreads();
  for (int e = e0 + threadIdx.x; e < e1; e += TPB)
    atomicAdd(&histL[dst[e] >> BSH], 1);
  __syncthreads();
  for (int b = threadIdx.x; b < MAXB; b += TPB){
    int c = histL[b];
    histL[b] = (c > 0) ? atomicAdd(&gcur[b], c) : 0;
  }
  __syncthreads();
  for (int e = e0 + threadIdx.x; e < e1; e += TPB){
    int d = dst[e];
    int b = d >> BSH;
    int slot = atomicAdd(&histL[b], 1);
    if (slot < BCAP)
      col[(size_t)b * BCAP + slot] = ((unsigned)(d & (BBW-1)) << 24) | (unsigned)src[e];
  }
}

// ---------------- conv1 aggregation: LDS-staged edges, src-tiled passes + BN stats --------
__global__ __launch_bounds__(TPB) void k_conv1agg(
    const float* __restrict__ h1, const unsigned* __restrict__ col,
    const int* __restrict__ gcur, float* __restrict__ agg, int N,
    float* __restrict__ stats)
{
  __shared__ float acc[16*BBW];       // acc[c*128 + dstlow]
  __shared__ unsigned ecache[BCAP];   // staged packed edges
  int b = blockIdx.x;
  for (int i = threadIdx.x; i < 16*BBW; i += TPB) acc[i] = 0.f;
  int len = gcur[b]; if (len > BCAP) len = BCAP;
  const unsigned* ce = col + (size_t)b * BCAP;
  for (int e = threadIdx.x; e < len; e += TPB) ecache[e] = ce[e];
  __syncthreads();
  int ntiles = (N + 65535) >> 16;
  for (int t = 0; t < ntiles; ++t){
    for (int e = threadIdx.x; e < len; e += TPB){
      unsigned pk = ecache[e];
      int s = (int)(pk & 0xFFFFFFu);
      if ((s >> 16) != t) continue;
      int dl = (int)(pk >> 24);
      const float4* hp = (const float4*)(h1 + (size_t)s * 16);
      float4 v0=hp[0], v1=hp[1], v2=hp[2], v3=hp[3];
      atomicAdd(&acc[ 0*BBW+dl], v0.x); atomicAdd(&acc[ 1*BBW+dl], v0.y);
      atomicAdd(&acc[ 2*BBW+dl], v0.z); atomicAdd(&acc[ 3*BBW+dl], v0.w);
      atomicAdd(&acc[ 4*BBW+dl], v1.x); atomicAdd(&acc[ 5*BBW+dl], v1.y);
      atomicAdd(&acc[ 6*BBW+dl], v1.z); atomicAdd(&acc[ 7*BBW+dl], v1.w);
      atomicAdd(&acc[ 8*BBW+dl], v2.x); atomicAdd(&acc[ 9*BBW+dl], v2.y);
      atomicAdd(&acc[10*BBW+dl], v2.z); atomicAdd(&acc[11*BBW+dl], v2.w);
      atomicAdd(&acc[12*BBW+dl], v3.x); atomicAdd(&acc[13*BBW+dl], v3.y);
      atomicAdd(&acc[14*BBW+dl], v3.z); atomicAdd(&acc[15*BBW+dl], v3.w);
    }
  }
  __syncthreads();
  int t = threadIdx.x;
  if (t < BBW){
    int d = b*BBW + t;
    if (d < N){
      float4* op = (float4*)(agg + (size_t)d * 16);
      #pragma unroll
      for (int q=0;q<4;++q)
        op[q] = make_float4(acc[(q*4+0)*BBW+t], acc[(q*4+1)*BBW+t],
                            acc[(q*4+2)*BBW+t], acc[(q*4+3)*BBW+t]);
    }
  }
  if (t < 32){
    int c = t & 15, r0 = (t>>4)*64;
    float sm=0.f, q=0.f;
    for (int r=0;r<64;++r){ float v = acc[c*BBW + r0 + r]; sm+=v; q+=v*v; }
    atomicAdd(&stats[c], sm);
    atomicAdd(&stats[16+c], q);
  }
}

// ---------------- BN1 + lrelu (in place) + p1 = h.Wrel, s1 = h.Wroot + br ----------------
__global__ __launch_bounds__(TPB) void k_bn1(
    float* __restrict__ h, const float* __restrict__ stats,
    const float* __restrict__ g, const float* __restrict__ be,
    const float* __restrict__ Wr, const float* __restrict__ br,
    const float* __restrict__ Wroot,
    float* __restrict__ p, float* __restrict__ s, int N, float invn)
{
  int i = blockIdx.x*TPB + threadIdx.x;
  if (i >= N) return;
  float* hp = h + (size_t)i*16;
  float pv=0.f, rv=0.f;
  #pragma unroll
  for (int c=0;c<16;++c){
    float mu = stats[c]*invn;
    float var = stats[16+c]*invn - mu*mu;
    float rsd = 1.0f / sqrtf(var + 1e-5f);
    float v = (hp[c]-mu)*rsd*g[c] + be[c];
    v = lrelu(v);
    hp[c] = v;
    pv += v*Wr[c];
    rv += v*Wroot[c];
  }
  p[i] = pv;
  s[i] = rv + br[0];
}

// ---------------- score aggregation: s[d] += sum p[src], one block per bucket --------------
// layer 2 needs no mask: bn2 zeroes p for dropped nodes; dropped dst rows are masked later.
__global__ __launch_bounds__(TPB) void k_score(
    const float* __restrict__ p, const unsigned* __restrict__ col,
    const int* __restrict__ gcur, float* __restrict__ s, int N)
{
  __shared__ float sacc[BBW];
  int b = blockIdx.x;
  if (threadIdx.x < BBW) sacc[threadIdx.x] = 0.f;
  __syncthreads();
  int len = gcur[b]; if (len > BCAP) len = BCAP;
  const unsigned* ce = col + (size_t)b * BCAP;
  for (int e = threadIdx.x; e < len; e += TPB){
    unsigned pk = ce[e];
    atomicAdd(&sacc[pk >> 24], p[pk & 0xFFFFFFu]);
  }
  __syncthreads();
  int d = b*BBW + threadIdx.x;
  if (threadIdx.x < BBW && d < N) s[d] += sacc[threadIdx.x];
}

// ---------------- radix-select stage 1: monotonic keys + top-16-bit histogram ----------------
__global__ __launch_bounds__(TPB) void k_keyhist(
    const float* __restrict__ s, const unsigned char* __restrict__ keep,
    unsigned* __restrict__ ukey, unsigned* __restrict__ hist, int N)
{
  int i = blockIdx.x*TPB + threadIdx.x;
  if (i >= N) return;
  unsigned u = 0u;
  if (!keep || keep[i]) u = fkey(s[i]);
  ukey[i] = u;
  if (u) atomicAdd(&hist[u>>16], 1u);
}

// ---------------- find threshold bucket (1 block) ----------------
__global__ __launch_bounds__(TPB) void k_findbucket(
    const unsigned* __restrict__ hist, unsigned k, unsigned* __restrict__ ctrl)
{
  __shared__ unsigned seg[TPB];
  __shared__ unsigned hb[256];
  __shared__ unsigned sS, scum;
  unsigned t = threadIdx.x;
  const uint4* h4 = (const uint4*)hist;
  unsigned ssum = 0;
  for (int q=0;q<64;++q){
    uint4 v = h4[t*64 + q];
    ssum += v.x + v.y + v.z + v.w;
  }
  seg[t] = ssum;
  __syncthreads();
  if (t == 0){
    unsigned cum = 0, S = 255;
    for (int s2=255; s2>=0; --s2){
      if (cum + seg[s2] >= k){ S = (unsigned)s2; break; }
      cum += seg[s2];
    }
    sS = S; scum = cum;
  }
  __syncthreads();
  hb[t] = hist[sS*256 + t];
  __syncthreads();
  if (t == 0){
    unsigned cum = scum, B = 0, need = 0;
    for (int b=255;b>=0;--b){
      unsigned h = hb[b];
      if (cum + h >= k){ B = sS*256 + (unsigned)b; need = k - cum; break; }
      cum += h;
    }
    ctrl[1] = B;
    ctrl[2] = need;
  }
}

// ---------------- collect boundary-bucket candidates; also re-zero hist for next use --------
__global__ __launch_bounds__(TPB) void k_collect(
    const unsigned* __restrict__ ukey, unsigned* __restrict__ cand,
    unsigned* __restrict__ ctrl, unsigned* __restrict__ hist, int N)
{
  int i = blockIdx.x*TPB + threadIdx.x;
  if (i < 65536) hist[i] = 0u;
  if (i < N){
    unsigned u = ukey[i];
    if ((u>>16) == ctrl[1]){
      unsigned pos = atomicAdd(&ctrl[6], 1u);
      if (pos < CAND_CAP) cand[pos] = u;
    }
  }
}

// ---------------- refine low 16 bits (1 block) -> T, needT; resets tie & cand counters ------
__global__ __launch_bounds__(TPB) void k_refine(
    const unsigned* __restrict__ cand, unsigned* __restrict__ ctrl)
{
  __shared__ unsigned h8[256];
  __shared__ unsigned sB2, sN2;
  unsigned t = threadIdx.x;
  unsigned L = ctrl[6];
  unsigned need = ctrl[2];
  h8[t] = 0u; __syncthreads();
  for (unsigned i=t; i<L; i+=TPB) atomicAdd(&h8[(cand[i]>>8)&0xFFu], 1u);
  __syncthreads();
  if (t == 0){
    unsigned cum=0, B2=0, n2=need;
    for (int b=255;b>=0;--b){
      unsigned h = h8[b];
      if (cum + h >= need){ B2=(unsigned)b; n2 = need - cum; break; }
      cum += h;
    }
    sB2 = B2; sN2 = n2;
  }
  __syncthreads();
  unsigned B2 = sB2, need2 = sN2;
  h8[t] = 0u; __syncthreads();
  for (unsigned i=t; i<L; i+=TPB){
    unsigned u = cand[i];
    if (((u>>8)&0xFFu) == B2) atomicAdd(&h8[u&0xFFu], 1u);
  }
  __syncthreads();
  if (t == 0){
    unsigned cum=0, B3=0, n3=need2;
    for (int b=255;b>=0;--b){
      unsigned h = h8[b];
      if (cum + h >= need2){ B3=(unsigned)b; n3 = need2 - cum; break; }
      cum += h;
    }
    unsigned B = ctrl[1];
    ctrl[3] = (B<<16) | (B2<<8) | B3; // threshold key T
    ctrl[4] = n3;                    // how many ==T to take
    ctrl[5] = 0u;                    // tie counter
    ctrl[6] = 0u;                    // cand counter (for next selection)
  }
}

// ---------------- mark keep1 + z1 = keep ? h1p * tanh(s1) : 0 ----------------
__global__ __launch_bounds__(TPB) void k_mark1(
    const unsigned* __restrict__ ukey, const float* __restrict__ s1,
    const float* __restrict__ h1p, float* __restrict__ z1,
    unsigned char* __restrict__ keep, unsigned* __restrict__ ctrl, int N)
{
  int i = blockIdx.x*TPB + threadIdx.x;
  if (i >= N) return;
  unsigned u = ukey[i], T = ctrl[3], needT = ctrl[4];
  bool sel = u > T;
  if (!sel && u == T) sel = (atomicAdd(&ctrl[5], 1u) < needT);
  keep[i] = sel ? (unsigned char)1 : (unsigned char)0;
  float tv = sel ? tanhf(s1[i]) : 0.0f;
  const float4* hp = (const float4*)(h1p + (size_t)i*16);
  float4* zp = (float4*)(z1 + (size_t)i*16);
  #pragma unroll
  for (int q=0;q<4;++q){
    float4 v = hp[q];
    zp[q] = make_float4(v.x*tv, v.y*tv, v.z*tv, v.w*tv);
  }
}

// ---------------- conv2: LDS-staged keep-filtered edges, src-tiled + GEMM + BN stats ------
__global__ __launch_bounds__(TPB) void k_conv2(
    const float* __restrict__ z1, const unsigned* __restrict__ col,
    const int* __restrict__ gcur, const unsigned char* __restrict__ keep,
    const float* __restrict__ W2, float* __restrict__ h2, int N,
    float* __restrict__ stats)
{
  __shared__ float acc[16*BBW];
  __shared__ float W2s[512];
  __shared__ unsigned ecache[BCAP];   // later reused as red[128][33]
  float (*red)[33] = (float(*)[33])ecache;
  for (int i = threadIdx.x; i < 16*BBW; i += TPB) acc[i] = 0.f;
  for (int i = threadIdx.x; i < 512; i += TPB) W2s[i] = W2[i];
  int b = blockIdx.x;
  int len = gcur[b]; if (len > BCAP) len = BCAP;
  const unsigned* ce = col + (size_t)b * BCAP;
  for (int e = threadIdx.x; e < len; e += TPB){
    unsigned pk = ce[e];
    ecache[e] = keep[pk & 0xFFFFFFu] ? pk : 0xFFFFFFFFu; // sentinel: tile 255
  }
  __syncthreads();
  int ntiles = (N + 65535) >> 16;
  for (int t = 0; t < ntiles; ++t){
    for (int e = threadIdx.x; e < len; e += TPB){
      unsigned pk = ecache[e];
      int s = (int)(pk & 0xFFFFFFu);
      if ((s >> 16) != t) continue;
      int dl = (int)(pk >> 24);
      const float4* zp = (const float4*)(z1 + (size_t)s * 16);
      float4 v0=zp[0], v1=zp[1], v2=zp[2], v3=zp[3];
      atomicAdd(&acc[ 0*BBW+dl], v0.x); atomicAdd(&acc[ 1*BBW+dl], v0.y);
      atomicAdd(&acc[ 2*BBW+dl], v0.z); atomicAdd(&acc[ 3*BBW+dl], v0.w);
      atomicAdd(&acc[ 4*BBW+dl], v1.x); atomicAdd(&acc[ 5*BBW+dl], v1.y);
      atomicAdd(&acc[ 6*BBW+dl], v1.z); atomicAdd(&acc[ 7*BBW+dl], v1.w);
      atomicAdd(&acc[ 8*BBW+dl], v2.x); atomicAdd(&acc[ 9*BBW+dl], v2.y);
      atomicAdd(&acc[10*BBW+dl], v2.z); atomicAdd(&acc[11*BBW+dl], v2.w);
      atomicAdd(&acc[12*BBW+dl], v3.x); atomicAdd(&acc[13*BBW+dl], v3.y);
      atomicAdd(&acc[14*BBW+dl], v3.z); atomicAdd(&acc[15*BBW+dl], v3.w);
    }
  }
  __syncthreads();  // passes done; ecache dead, safe to reuse as red
  int t = threadIdx.x;
  float h[32];
  #pragma unroll
  for (int c2=0;c2<32;++c2) h[c2]=0.f;
  if (t < BBW){
    int d = b*BBW + t;
    bool act = (d < N) && keep[d];
    if (act){
      #pragma unroll
      for (int c=0;c<16;++c){
        float av = acc[c*BBW + t];
        const float* wrow = &W2s[c*32];
        #pragma unroll
        for (int c2=0;c2<32;++c2) h[c2] += av*wrow[c2];
      }
      float4* op = (float4*)(h2 + (size_t)d*32);
      #pragma unroll
      for (int q=0;q<8;++q)
        op[q] = make_float4(h[q*4+0],h[q*4+1],h[q*4+2],h[q*4+3]);
    }
    #pragma unroll
    for (int c2=0;c2<32;++c2) red[t][c2]=h[c2];
  }
  __syncthreads();
  if (t < 64){
    int c = t & 31, r0 = (t>>5)*64;
    float sm=0.f, q=0.f;
    for (int r=0;r<64;++r){ float v = red[r0+r][c]; sm+=v; q+=v*v; }
    atomicAdd(&stats[c], sm);
    atomicAdd(&stats[32+c], q);
  }
}

// ---------------- BN2 + lrelu (kept rows) + p2, s2; zero p/s for dropped ----------------
__global__ __launch_bounds__(TPB) void k_bn2(
    float* __restrict__ h, const float* __restrict__ stats,
    const float* __restrict__ g, const float* __restrict__ be,
    const float* __restrict__ Wr, const float* __restrict__ br,
    const float* __restrict__ Wroot, const unsigned char* __restrict__ keep,
    float* __restrict__ p, float* __restrict__ s, int N, float invn)
{
  int i = blockIdx.x*TPB + threadIdx.x;
  if (i >= N) return;
  if (!keep[i]){ p[i] = 0.f; s[i] = 0.f; return; }
  float* hp = h + (size_t)i*32;
  float pv=0.f, rv=0.f;
  #pragma unroll
  for (int c=0;c<32;++c){
    float mu = stats[c]*invn;
    float var = stats[32+c]*invn - mu*mu;
    float rsd = 1.0f / sqrtf(var + 1e-5f);
    float v = (hp[c]-mu)*rsd*g[c] + be[c];
    v = lrelu(v);
    hp[c] = v;
    pv += v*Wr[c];
    rv += v*Wroot[c];
  }
  p[i] = pv;
  s[i] = rv + br[0];
}

// ---------------- final: select top-k2, pooled += h2p * tanh(s2) ----------------
__global__ __launch_bounds__(TPB) void k_final(
    const unsigned* __restrict__ ukey, const float* __restrict__ s2,
    const float* __restrict__ h2p, unsigned* __restrict__ ctrl,
    float* __restrict__ pooled, int N)
{
  __shared__ float red[TPB][33];
  int i = blockIdx.x*TPB + threadIdx.x;
  float contrib[32];
  #pragma unroll
  for (int c=0;c<32;++c) contrib[c]=0.f;
  if (i < N){
    unsigned u = ukey[i], T = ctrl[3], needT = ctrl[4];
    bool sel = u > T;
    if (!sel && u == T) sel = (atomicAdd(&ctrl[5], 1u) < needT);
    if (sel){
      float tv = tanhf(s2[i]);
      const float* hp = h2p + (size_t)i*32;
      #pragma unroll
      for (int c=0;c<32;++c) contrib[c] = hp[c]*tv;
    }
  }
  #pragma unroll
  for (int c=0;c<32;++c) red[threadIdx.x][c]=contrib[c];
  __syncthreads();
  if (threadIdx.x < 64){
    int c = threadIdx.x & 31, r0 = (threadIdx.x>>5)*128;
    float sm=0.f;
    for (int r=0;r<128;++r) sm += red[r0+r][c];
    atomicAdd(&pooled[c], sm);
  }
}

// ---------------- tiny MLP 32->8->4->2 ----------------
__global__ void k_mlp(const float* __restrict__ pooled,
    const float* __restrict__ fw1, const float* __restrict__ fb1,
    const float* __restrict__ fw2, const float* __restrict__ fb2,
    const float* __restrict__ fw3, const float* __restrict__ fb3,
    float* __restrict__ out)
{
  if (blockIdx.x==0 && threadIdx.x==0){
    float a[8];
    for (int o=0;o<8;++o){
      float t = fb1[o];
      for (int c=0;c<32;++c) t += pooled[c]*fw1[c*8+o];
      a[o] = lrelu(t);
    }
    float b[4];
    for (int o=0;o<4;++o){
      float t = fb2[o];
      for (int c=0;c<8;++c) t += a[c]*fw2[c*4+o];
      b[o] = lrelu(t);
    }
    for (int o=0;o<2;++o){
      float t = fb3[o];
      for (int c=0;c<4;++c) t += b[c]*fw3[c*2+o];
      out[o] = lrelu(t);
    }
  }
}

extern "C" void kernel_launch(void* const* d_in, const int* in_sizes, int n_in,
                              void* d_out, int out_size, void* d_ws, size_t ws_size,
                              hipStream_t stream)
{
  const float* x      = (const float*)d_in[0];
  const int*   ei     = (const int*)  d_in[1];
  // d_in[2] edge_weigth, d_in[3] batch: unused by the reference math
  const float* W1     = (const float*)d_in[4];
  const float* g1     = (const float*)d_in[6];
  const float* be1    = (const float*)d_in[7];
  const float* Wr1    = (const float*)d_in[8];
  const float* br1    = (const float*)d_in[9];
  const float* Wroot1 = (const float*)d_in[10];
  const float* W2     = (const float*)d_in[11];
  const float* g2     = (const float*)d_in[13];
  const float* be2    = (const float*)d_in[14];
  const float* Wr2    = (const float*)d_in[15];
  const float* br2    = (const float*)d_in[16];
  const float* Wroot2 = (const float*)d_in[17];
  const float* fw1    = (const float*)d_in[18];
  const float* fb1    = (const float*)d_in[19];
  const float* fw2    = (const float*)d_in[20];
  const float* fb2    = (const float*)d_in[21];
  const float* fw3    = (const float*)d_in[22];
  const float* fb3    = (const float*)d_in[23];

  int N = in_sizes[0] / 128;
  int E = in_sizes[1] / 2;
  const int* srcp = ei;
  const int* dstp = ei + E;
  int k1 = (N + 1) / 2;
  int k2 = (k1 + 1) / 2;
  int NB  = (N + BBW - 1) >> BSH;     // number of buckets (<= MAXB)
  int nbN = (N + TPB - 1) / TPB;

  char* w = (char*)d_ws;
  size_t off = 0;
  auto alloc = [&](size_t bytes)->char* {
    char* ptr = w + off;
    off += (bytes + 255) & ~(size_t)255;
    return ptr;
  };
  // --- zeroed prefix: gcur | hist | ctrl(+stats+pooled) ---
  int*      gcur = (int*)     alloc((size_t)MAXB*4);
  unsigned* hist = (unsigned*)alloc(65536*4);
  unsigned* ctrl = (unsigned*)alloc(1024);
  size_t zerosz = off;
  float* stats1 = (float*)(ctrl + 32);   // 32 floats
  float* stats2 = (float*)(ctrl + 96);   // 64 floats
  float* pooled = (float*)(ctrl + 160);  // 32 floats
  // --- rest of workspace ---
  unsigned* col  = (unsigned*)alloc((size_t)NB*BCAP*4);
  float*    h1   = (float*)   alloc((size_t)N*16*4); // later reused as z1
  float*    agg1 = (float*)   alloc((size_t)N*16*4); // later h1p (in place)
  float*    h2   = (float*)   alloc((size_t)N*32*4); // later h2p (in place)
  float*    sbuf = (float*)   alloc((size_t)N*4);    // s1 then s2
  float*    pbuf = (float*)   alloc((size_t)N*4);    // p1 then p2
  unsigned* ukey = (unsigned*)alloc((size_t)N*4);
  unsigned char* keep = (unsigned char*)alloc((size_t)N);
  unsigned* cand = (unsigned*)alloc((size_t)CAND_CAP*4);
  (void)ws_size; (void)n_in; (void)out_size;

  hipMemsetAsync(d_ws, 0, zerosz, stream);

  // layer 1
  k_gemm1     <<<(N + 2*TPB - 1)/(2*TPB), TPB, 0, stream>>>(x, W1, h1, N);
  k_bin       <<<BIN_BLOCKS, TPB, 0, stream>>>(srcp, dstp, E, gcur, col);
  k_conv1agg  <<<NB, TPB, 0, stream>>>(h1, col, gcur, agg1, N, stats1);
  k_bn1       <<<nbN, TPB, 0, stream>>>(agg1, stats1, g1, be1, Wr1, br1, Wroot1,
                                        pbuf, sbuf, N, 1.0f/(float)N);
  k_score     <<<NB, TPB, 0, stream>>>(pbuf, col, gcur, sbuf, N);
  // SAG pool 1 (radix select k1)
  k_keyhist   <<<nbN, TPB, 0, stream>>>(sbuf, nullptr, ukey, hist, N);
  k_findbucket<<<1, TPB, 0, stream>>>(hist, (unsigned)k1, ctrl);
  k_collect   <<<nbN, TPB, 0, stream>>>(ukey, cand, ctrl, hist, N);
  k_refine    <<<1, TPB, 0, stream>>>(cand, ctrl);
  k_mark1     <<<nbN, TPB, 0, stream>>>(ukey, sbuf, agg1, h1, keep, ctrl, N);
  // layer 2
  k_conv2     <<<NB, TPB, 0, stream>>>(h1, col, gcur, keep, W2, h2, N, stats2);
  k_bn2       <<<nbN, TPB, 0, stream>>>(h2, stats2, g2, be2, Wr2, br2, Wroot2, keep,
                                        pbuf, sbuf, N, 1.0f/(float)k1);
  k_score     <<<NB, TPB, 0, stream>>>(pbuf, col, gcur, sbuf, N);
  // SAG pool 2 (radix select k2) + global pool
  k_keyhist   <<<nbN, TPB, 0, stream>>>(sbuf, keep, ukey, hist, N);
  k_findbucket<<<1, TPB, 0, stream>>>(hist, (unsigned)k2, ctrl);
  k_collect   <<<nbN, TPB, 0, stream>>>(ukey, cand, ctrl, hist, N);
  k_refine    <<<1, TPB, 0, stream>>>(cand, ctrl);
  k_final     <<<nbN, TPB, 0, stream>>>(ukey, sbuf, h2, ctrl, pooled, N);
  k_mlp       <<<1, 64, 0, stream>>>(pooled, fw1, fb1, fw2, fb2, fw3, fb3, (float*)d_out);
}